// Round 6
// baseline (611.522 us; speedup 1.0000x reference)
//
#include <hip/hip_runtime.h>
#include <hip/hip_bf16.h>

#define NRAYS 4096
#define NS 256
#define G 160
#define G2 (160*160)
#define G3 (160*160*160)
#define K0DIM 12
#define WIDTH 128
#define CHUNK 32
#define NCHUNK 8
#define HBS 136              // h0B bf16 row stride (272 B: 16B-aligned rows, 2-way banks = free)
#define ACT_SHIFT_F (-4.5951198501345889f)
#define TNEAR 0.2f
#define TFAR 1.8f

typedef unsigned short u16;
typedef unsigned int u32;
typedef __attribute__((ext_vector_type(8))) short short8;   // 8 bf16 = 4 VGPRs (MFMA A/B frag)
typedef __attribute__((ext_vector_type(4))) float floatx4;  // MFMA C/D frag

// W1f[kq][qsub][col][j]: B-frag for (kq, quarter qsub, output col) = 16 contiguous bytes
#define W1F_IDX(kq, qs, n) (((((kq)<<2) + (qs)) * 128 + (n)) << 3)

__device__ __forceinline__ float bf2f(u16 u) {
    union { u32 i; float f; } v; v.i = ((u32)u) << 16; return v.f;
}
__device__ __forceinline__ u16 f2bf(float f) {   // RTNE fp32 -> bf16
    union { float f; u32 u; } v; v.f = f;
    u32 r = v.u + 0x7FFFu + ((v.u >> 16) & 1u);
    return (u16)(r >> 16);
}

__device__ __forceinline__ float loadv(const float* p, int i) { return p[i]; }
__device__ __forceinline__ float loadv(const u16* p, int i)   { return bf2f(p[i]); }
__device__ __forceinline__ void storev(float* p, int i, float v) { p[i] = v; }
__device__ __forceinline__ void storev(u16* p, int i, float v)   { p[i] = f2bf(v); }
__device__ __forceinline__ u16 as_bf16(u16 v)   { return v; }
__device__ __forceinline__ u16 as_bf16(float v) { return f2bf(v); }

// z-quad raw vector type per dtype (density + fallback path)
template <typename T> struct QT;
template <> struct QT<u16>   { using type = ushort4; };
template <> struct QT<float> { using type = float4;  };

__device__ __forceinline__ void zpair(const ushort4& q, int d, float& v0, float& v1) {
    u16 r0 = (d == 0) ? q.x : ((d == 1) ? q.y : q.z);
    u16 r1 = (d == 0) ? q.y : ((d == 1) ? q.z : q.w);
    v0 = bf2f(r0); v1 = bf2f(r1);
}
__device__ __forceinline__ void zpair(const float4& q, int d, float& v0, float& v1) {
    v0 = (d == 0) ? q.x : ((d == 1) ? q.y : q.z);
    v1 = (d == 0) ? q.y : ((d == 1) ? q.z : q.w);
}

struct Coords { int idx; float fx, fy, fz; };
__device__ __forceinline__ Coords coords_for(float px, float py, float pz) {
    float gx = fminf(fmaxf((px + 1.0f) * 79.5f, 0.0f), 159.0f);
    float gy = fminf(fmaxf((py + 1.0f) * 79.5f, 0.0f), 159.0f);
    float gz = fminf(fmaxf((pz + 1.0f) * 79.5f, 0.0f), 159.0f);
    int ix = (int)gx; if (ix > 158) ix = 158;
    int iy = (int)gy; if (iy > 158) iy = 158;
    int iz = (int)gz; if (iz > 158) iz = 158;
    Coords c;
    c.idx = (ix * G + iy) * G + iz;
    c.fx = gx - (float)ix; c.fy = gy - (float)iy; c.fz = gz - (float)iz;
    return c;
}

struct CoordsE { int base; int d; float fx, fy, fz; };
__device__ __forceinline__ CoordsE coords_e(float px, float py, float pz) {
    float gx = fminf(fmaxf((px + 1.0f) * 79.5f, 0.0f), 159.0f);
    float gy = fminf(fmaxf((py + 1.0f) * 79.5f, 0.0f), 159.0f);
    float gz = fminf(fmaxf((pz + 1.0f) * 79.5f, 0.0f), 159.0f);
    int ix = (int)gx; if (ix > 158) ix = 158;
    int iy = (int)gy; if (iy > 158) iy = 158;
    int iz = (int)gz; if (iz > 158) iz = 158;
    int ze = iz & ~1; if (ze > 156) ze = 156;
    CoordsE c;
    c.base = (ix * G + iy) * G + ze;
    c.d = iz - ze;
    c.fx = gx - (float)ix; c.fy = gy - (float)iy; c.fz = gz - (float)iz;
    return c;
}

__device__ __forceinline__ int wild16(u16 u) {
    int e = (u >> 7) & 0xFF;
    int m = u & 0x7F;
    float v = bf2f(u);
    return (e == 0xFF || (e == 0 && m != 0) || fabsf(v) > 32.0f) ? 1 : 0;
}

// ---------------- k0 transpose: channel-major -> voxel-interleaved bf16 ----------------
// out[((x*G+y)*G+z)*12 + ch] = bf16(k0[ch][x][y][z]).  One block per (x,y) column.
template <typename T, int MODE>
__global__ __launch_bounds__(64)
void transpose_k0(const T* __restrict__ k0, u16* __restrict__ outg,
                  const u16* __restrict__ rdraw)
{
    const int tid = threadIdx.x;
    int pred = wild16(rdraw[tid]) + wild16(rdraw[tid + 64]);
    int bad = __syncthreads_count(pred != 0);
    if ((bad >= 2) != (MODE == 1)) return;

    const int b = blockIdx.x;              // 0..25599
    const int x = b / G, y = b - x * G;
    const int colbase = (x * G + y) * G;

    __shared__ __align__(4) u16 tile[G * 12];   // 3840 B
    #pragma unroll
    for (int ch = 0; ch < 12; ch++)
        for (int z = tid; z < G; z += 64)
            tile[z * 12 + ch] = as_bf16(k0[(size_t)ch * G3 + colbase + z]);
    __syncthreads();

    const u32* t32 = (const u32*)tile;
    u32* d32 = (u32*)outg;
    const int obase = colbase * 6;         // (colbase*12 u16) / 2
    for (int i = tid; i < G * 6; i += 64) d32[obase + i] = t32[i];
}

// ---------------- fused DVGO kernel ----------------
template <typename T, typename OT, int MODE, int LAYOUT>
__global__ __launch_bounds__(256, 3)
void dvgo_fused(const T* __restrict__ rays_o, const T* __restrict__ rays_d,
                const T* __restrict__ density, const T* __restrict__ k0,
                const T* __restrict__ W0, const T* __restrict__ b0,
                const T* __restrict__ W1, const T* __restrict__ b1,
                const T* __restrict__ W2, const T* __restrict__ b2,
                OT* __restrict__ out, const u16* __restrict__ rdraw,
                const u16* __restrict__ wsgrid)
{
    const int tid = threadIdx.x;

    // self-decide dtype (uniform across block; no LDS touched yet)
    {
        int pred = (tid < 128) ? wild16(rdraw[tid]) : 0;
        int bad = __syncthreads_count(pred);
        if ((bad >= 4) != (MODE == 1)) return;
    }

    using qvec = typename QT<T>::type;

    __shared__ __align__(16) u16   W1f[WIDTH * WIDTH];     // 32768 B  swizzled B-frag layout
    __shared__ __align__(16) u16   h0B[CHUNK * HBS];       // 8704 B   h0 bf16 [sample][k]
    __shared__ __align__(16) u16   W0f[WIDTH * 16];        // 4096 B   W0T[n][k], k 12..15 = 0
    __shared__ __align__(16) u16   featB[CHUNK * 16];      // 1024 B   feat bf16 [sample][k<=15]
    __shared__ __align__(16) float W2Tf[3 * WIDTH];        // 1536 B
    __shared__ float p2[CHUNK * 6];                        // 768 B  [s][nh][c]
    __shared__ float base0[WIDTH];
    __shared__ float b1s[WIDTH];
    __shared__ float b2s[3];
    __shared__ float vembs[27];
    __shared__ float wts[NS];
    __shared__ float red[96];
    __shared__ float ainvs;

    const int r = blockIdx.x;

    const float o0 = loadv(rays_o, r*3+0);
    const float o1 = loadv(rays_o, r*3+1);
    const float o2 = loadv(rays_o, r*3+2);
    const float d0 = loadv(rays_d, r*3+0);
    const float d1 = loadv(rays_d, r*3+1);
    const float d2 = loadv(rays_d, r*3+2);

    // ---- stage weights into LDS ----
    for (int idx = tid; idx < WIDTH*WIDTH; idx += 256) {
        int k = idx >> 7, n = idx & 127;
        W1f[W1F_IDX(k >> 5, (k >> 3) & 3, n) + (k & 7)] = f2bf(loadv(W1, idx));
    }
    for (int i = tid; i < WIDTH*16; i += 256) {
        int n = i >> 4, k = i & 15;
        W0f[i] = (k < K0DIM) ? f2bf(loadv(W0, k*WIDTH + n)) : (u16)0;
    }
    for (int i = tid; i < CHUNK*4; i += 256)          // featB k=12..15 stays 0 forever
        featB[(i >> 2)*16 + 12 + (i & 3)] = 0;
    for (int k = tid; k < 3*WIDTH; k += 256) {
        int c = k >> 7, i = k & 127;
        W2Tf[k] = loadv(W2, i*3 + c);
    }
    if (tid < WIDTH) b1s[tid] = loadv(b1, tid);
    if (tid < 3)     b2s[tid] = loadv(b2, tid);

    // ---- view embedding (per-ray constant) ----
    if (tid < 27) {
        float inv = rsqrtf(d0*d0 + d1*d1 + d2*d2);
        float v0 = d0*inv, v1 = d1*inv, v2 = d2*inv;
        float val;
        if (tid < 3) {
            val = (tid == 0) ? v0 : ((tid == 1) ? v1 : v2);
        } else if (tid < 15) {
            int t2 = tid - 3; int dd = t2 >> 2; int p = t2 & 3;
            float vd = (dd == 0) ? v0 : ((dd == 1) ? v1 : v2);
            val = sinf(vd * (float)(1 << p));
        } else {
            int t2 = tid - 15; int dd = t2 >> 2; int p = t2 & 3;
            float vd = (dd == 0) ? v0 : ((dd == 1) ? v1 : v2);
            val = cosf(vd * (float)(1 << p));
        }
        vembs[tid] = val;
    }
    __syncthreads();

    // ---- base0 = b0 + vemb @ W0[12:39]  (per-ray) ----
    if (tid < WIDTH) {
        float a = loadv(b0, tid);
        #pragma unroll
        for (int i = 0; i < 27; i++)
            a += vembs[i] * loadv(W0, (K0DIM + i)*WIDTH + tid);
        base0[tid] = a;
    }

    // ---- alpha for my sample (quad-load gather on density) ----
    {
        int s = tid;
        float tv = TNEAR + (TFAR - TNEAR) * ((float)s * (1.0f/(float)(NS-1)));
        CoordsE c = coords_e(o0 + d0*tv, o1 + d1*tv, o2 + d2*tv);
        qvec q00 = *(const qvec*)(density + c.base);
        qvec q01 = *(const qvec*)(density + c.base + G);
        qvec q10 = *(const qvec*)(density + c.base + G2);
        qvec q11 = *(const qvec*)(density + c.base + G2 + G);
        float a0,a1,b0v,b1v,c0v,c1v,d0v,d1v;
        zpair(q00, c.d, a0, a1); zpair(q01, c.d, b0v, b1v);
        zpair(q10, c.d, c0v, c1v); zpair(q11, c.d, d0v, d1v);
        float c00 = a0*(1.0f-c.fz) + a1*c.fz;
        float c01 = b0v*(1.0f-c.fz) + b1v*c.fz;
        float c10 = c0v*(1.0f-c.fz) + c1v*c.fz;
        float c11 = d0v*(1.0f-c.fz) + d1v*c.fz;
        float e0 = c00*(1.0f-c.fy) + c01*c.fy;
        float e1 = c10*(1.0f-c.fy) + c11*c.fy;
        float sigma = e0*(1.0f-c.fx) + e1*c.fx;
        float alpha = 1.0f - rsqrtf(1.0f + __expf(sigma + ACT_SHIFT_F));
        wts[s] = alpha;
    }
    __syncthreads();

    // ---- serial transmittance scan ----
    if (tid == 0) {
        float w = 1.0f;
        for (int s = 0; s < NS; s++) {
            float a = wts[s];
            wts[s] = a * w;
            w *= (1.0f - a + 1e-10f);
        }
        ainvs = w;
    }
    __syncthreads();

    // ---- per-thread role constants ----
    const int lane = tid & 63;
    const int wvid = tid >> 6;
    const int mt   = wvid & 1;
    const int nh   = wvid >> 1;
    const int q    = lane >> 4;
    const int ncol = lane & 15;
    const int arow = mt*16 + ncol;
    const int kcol = q * 8;
    const int drow0 = mt*16 + q*4;

    const int ch0 = tid >> 5;              // task 0 channel (0..7)
    const int sl0 = tid & 31;
    const int ch1 = 8 + (tid >> 5);        // task 1 channel (8..11) for tid<128
    const int sl1 = tid & 31;
    const bool has1 = (tid < 128);

    float rgbacc = 0.0f;

    // ---- shared phase macros ----
    #define L0_BLOCK                                                            \
        {                                                                       \
            short8 af0 = {};                                                    \
            short8 bf0 = {}, bf1 = {}, bf2v = {}, bf3 = {};                     \
            if (q < 2) {                                                        \
                af0  = *(const short8*)&featB[arow*16 + kcol];                  \
                bf0  = *(const short8*)&W0f[(nh*64 +  0 + ncol)*16 + kcol];     \
                bf1  = *(const short8*)&W0f[(nh*64 + 16 + ncol)*16 + kcol];     \
                bf2v = *(const short8*)&W0f[(nh*64 + 32 + ncol)*16 + kcol];     \
                bf3  = *(const short8*)&W0f[(nh*64 + 48 + ncol)*16 + kcol];     \
            }                                                                   \
            floatx4 acc0[4];                                                    \
            _Pragma("unroll")                                                   \
            for (int t = 0; t < 4; t++) {                                       \
                float v = base0[nh*64 + t*16 + ncol];                           \
                acc0[t] = (floatx4){v, v, v, v};                                \
            }                                                                   \
            acc0[0] = __builtin_amdgcn_mfma_f32_16x16x32_bf16(af0, bf0,  acc0[0], 0, 0, 0); \
            acc0[1] = __builtin_amdgcn_mfma_f32_16x16x32_bf16(af0, bf1,  acc0[1], 0, 0, 0); \
            acc0[2] = __builtin_amdgcn_mfma_f32_16x16x32_bf16(af0, bf2v, acc0[2], 0, 0, 0); \
            acc0[3] = __builtin_amdgcn_mfma_f32_16x16x32_bf16(af0, bf3,  acc0[3], 0, 0, 0); \
            _Pragma("unroll")                                                   \
            for (int t = 0; t < 4; t++) {                                       \
                int j = nh*64 + t*16 + ncol;                                    \
                _Pragma("unroll")                                               \
                for (int rI = 0; rI < 4; rI++)                                  \
                    h0B[(drow0 + rI)*HBS + j] = f2bf(fmaxf(acc0[t][rI], 0.0f)); \
            }                                                                   \
        }

    #define L1_L2_BLOCK(C0)                                                     \
        {                                                                       \
            floatx4 acc[4];                                                     \
            _Pragma("unroll")                                                   \
            for (int t = 0; t < 4; t++) {                                       \
                float bj = b1s[nh*64 + t*16 + ncol];                            \
                acc[t] = (floatx4){bj, bj, bj, bj};                             \
            }                                                                   \
            _Pragma("unroll")                                                   \
            for (int kq = 0; kq < 4; kq++) {                                    \
                short8 af = *(const short8*)&h0B[arow*HBS + kq*32 + kcol];      \
                _Pragma("unroll")                                               \
                for (int t = 0; t < 4; t++) {                                   \
                    short8 bf = *(const short8*)&W1f[W1F_IDX(kq, q, nh*64 + t*16 + ncol)]; \
                    acc[t] = __builtin_amdgcn_mfma_f32_16x16x32_bf16(af, bf, acc[t], 0, 0, 0); \
                }                                                               \
            }                                                                   \
            float p[3][4];                                                      \
            _Pragma("unroll")                                                   \
            for (int c = 0; c < 3; c++)                                         \
                { p[c][0]=0; p[c][1]=0; p[c][2]=0; p[c][3]=0; }                 \
            _Pragma("unroll")                                                   \
            for (int t = 0; t < 4; t++) {                                       \
                int j = nh*64 + t*16 + ncol;                                    \
                float w20 = W2Tf[j], w21 = W2Tf[WIDTH + j], w22 = W2Tf[2*WIDTH + j]; \
                _Pragma("unroll")                                               \
                for (int rI = 0; rI < 4; rI++) {                                \
                    float h = fmaxf(acc[t][rI], 0.0f);                          \
                    p[0][rI] += h * w20;                                        \
                    p[1][rI] += h * w21;                                        \
                    p[2][rI] += h * w22;                                        \
                }                                                               \
            }                                                                   \
            _Pragma("unroll")                                                   \
            for (int m = 1; m <= 8; m <<= 1) {                                  \
                _Pragma("unroll")                                               \
                for (int c = 0; c < 3; c++) {                                   \
                    _Pragma("unroll")                                           \
                    for (int rI = 0; rI < 4; rI++)                              \
                        p[c][rI] += __shfl_xor(p[c][rI], m, 64);                \
                }                                                               \
            }                                                                   \
            if (ncol == 0) {                                                    \
                _Pragma("unroll")                                               \
                for (int rI = 0; rI < 4; rI++) {                                \
                    _Pragma("unroll")                                           \
                    for (int c = 0; c < 3; c++)                                 \
                        p2[(drow0 + rI)*6 + nh*3 + c] = p[c][rI];               \
                }                                                               \
            }                                                                   \
        }

    #define SIGMOID_ACC(C0)                                                     \
        if (tid < 96) {                                                         \
            int c = tid >> 5, s = tid & 31;                                     \
            float acc2 = b2s[c] + p2[s*6 + c] + p2[s*6 + 3 + c];                \
            float rgb = 1.0f / (1.0f + __expf(-acc2));                          \
            rgbacc += wts[(C0) + s] * rgb;                                      \
        }

    if constexpr (LAYOUT == 1) {
        // ---- interleaved-grid gather (wsgrid), prefetch depth 2 ----
        #define ISSUE_I(CH, SL, C0N, RAW, FR)                                   \
            { int s_ = (C0N) + (SL);                                            \
              float tv_ = TNEAR + (TFAR - TNEAR) * ((float)s_ * (1.0f/255.0f)); \
              Coords c_ = coords_for(o0 + d0*tv_, o1 + d1*tv_, o2 + d2*tv_);    \
              int a_ = c_.idx*12 + (CH);                                        \
              RAW[0] = wsgrid[a_];          RAW[1] = wsgrid[a_ + 12];           \
              RAW[2] = wsgrid[a_ + 1920];   RAW[3] = wsgrid[a_ + 1932];         \
              RAW[4] = wsgrid[a_ + 307200]; RAW[5] = wsgrid[a_ + 307212];       \
              RAW[6] = wsgrid[a_ + 309120]; RAW[7] = wsgrid[a_ + 309132];       \
              FR[0] = c_.fx; FR[1] = c_.fy; FR[2] = c_.fz; }

        #define COMMIT_I(CH, SL, RAW, FR)                                       \
            { float fz_ = FR[2], fy_ = FR[1], fx_ = FR[0];                      \
              float c00_ = bf2f(RAW[0])*(1.0f-fz_) + bf2f(RAW[1])*fz_;          \
              float c01_ = bf2f(RAW[2])*(1.0f-fz_) + bf2f(RAW[3])*fz_;          \
              float c10_ = bf2f(RAW[4])*(1.0f-fz_) + bf2f(RAW[5])*fz_;          \
              float c11_ = bf2f(RAW[6])*(1.0f-fz_) + bf2f(RAW[7])*fz_;          \
              float e0_ = c00_*(1.0f-fy_) + c01_*fy_;                           \
              float e1_ = c10_*(1.0f-fy_) + c11_*fy_;                           \
              featB[(SL)*16 + (CH)] = f2bf(e0_*(1.0f-fx_) + e1_*fx_); }

        #define CHUNK_BODY_I(C0, RA, FA, RB, FB)                                \
            {                                                                   \
                COMMIT_I(ch0, sl0, RA, FA);                                     \
                if (has1) COMMIT_I(ch1, sl1, RB, FB);                           \
                __syncthreads();                                                \
                L0_BLOCK;                                                       \
                __syncthreads();                                                \
                if ((C0) + 64 < NS) {                                           \
                    ISSUE_I(ch0, sl0, (C0) + 64, RA, FA);                       \
                    if (has1) ISSUE_I(ch1, sl1, (C0) + 64, RB, FB);             \
                }                                                               \
                L1_L2_BLOCK(C0);                                                \
                __syncthreads();                                                \
                SIGMOID_ACC(C0);                                                \
            }

        u16 rwA[8], rwB[8], rwC[8], rwD[8];
        float fA[3], fB[3], fC[3], fD[3];
        ISSUE_I(ch0, sl0, 0, rwA, fA);
        if (has1) ISSUE_I(ch1, sl1, 0, rwB, fB);
        ISSUE_I(ch0, sl0, 32, rwC, fC);
        if (has1) ISSUE_I(ch1, sl1, 32, rwD, fD);

        for (int cp = 0; cp < 4; cp++) {
            int c0 = cp * 64;
            CHUNK_BODY_I(c0,      rwA, fA, rwB, fB);
            CHUNK_BODY_I(c0 + 32, rwC, fC, rwD, fD);
        }
        #undef ISSUE_I
        #undef COMMIT_I
        #undef CHUNK_BODY_I
    } else {
        // ---- fallback: channel-major quad gather on k0, prefetch depth 1 ----
        qvec qa[4], qb[4];
        CoordsE cea, ceb;

        #define ISSUE_Q(CH, SL, C0N, Q, CE)                                     \
            { int s_ = (C0N) + (SL);                                            \
              float tv_ = TNEAR + (TFAR - TNEAR) * ((float)s_ * (1.0f/255.0f)); \
              CE = coords_e(o0 + d0*tv_, o1 + d1*tv_, o2 + d2*tv_);             \
              const T* g_ = k0 + (size_t)(CH)*G3;                               \
              Q[0] = *(const qvec*)(g_ + CE.base);                              \
              Q[1] = *(const qvec*)(g_ + CE.base + G);                          \
              Q[2] = *(const qvec*)(g_ + CE.base + G2);                         \
              Q[3] = *(const qvec*)(g_ + CE.base + G2 + G); }

        #define COMMIT_Q(CH, SL, Q, CE)                                         \
            { float a0_,a1_,b0_,b1_,c0_,c1_,d0_,d1_;                            \
              zpair(Q[0], CE.d, a0_, a1_); zpair(Q[1], CE.d, b0_, b1_);         \
              zpair(Q[2], CE.d, c0_, c1_); zpair(Q[3], CE.d, d0_, d1_);         \
              float fz_ = CE.fz, fy_ = CE.fy, fx_ = CE.fx;                      \
              float c00_ = a0_*(1.0f-fz_) + a1_*fz_;                            \
              float c01_ = b0_*(1.0f-fz_) + b1_*fz_;                            \
              float c10_ = c0_*(1.0f-fz_) + c1_*fz_;                            \
              float c11_ = d0_*(1.0f-fz_) + d1_*fz_;                            \
              float e0_ = c00_*(1.0f-fy_) + c01_*fy_;                           \
              float e1_ = c10_*(1.0f-fy_) + c11_*fy_;                           \
              featB[(SL)*16 + (CH)] = f2bf(e0_*(1.0f-fx_) + e1_*fx_); }

        ISSUE_Q(ch0, sl0, 0, qa, cea);
        if (has1) ISSUE_Q(ch1, sl1, 0, qb, ceb);

        for (int cc = 0; cc < NCHUNK; cc++) {
            const int c0 = cc * CHUNK;
            COMMIT_Q(ch0, sl0, qa, cea);
            if (has1) COMMIT_Q(ch1, sl1, qb, ceb);
            __syncthreads();
            L0_BLOCK;
            __syncthreads();
            if (cc + 1 < NCHUNK) {
                ISSUE_Q(ch0, sl0, c0 + CHUNK, qa, cea);
                if (has1) ISSUE_Q(ch1, sl1, c0 + CHUNK, qb, ceb);
            }
            L1_L2_BLOCK(c0);
            __syncthreads();
            SIGMOID_ACC(c0);
        }
        #undef ISSUE_Q
        #undef COMMIT_Q
    }

    if (tid < 96) red[tid] = rgbacc;
    __syncthreads();
    if (tid < 3) {
        float s = 0.0f;
        #pragma unroll
        for (int k = 0; k < 32; k++) s += red[tid*32 + k];
        storev(out, r*3 + tid, s + ainvs);
    }
    #undef L0_BLOCK
    #undef L1_L2_BLOCK
    #undef SIGMOID_ACC
}

extern "C" void kernel_launch(void* const* d_in, const int* in_sizes, int n_in,
                              void* d_out, int out_size, void* d_ws, size_t ws_size,
                              hipStream_t stream) {
    const u16* rdraw = (const u16*)d_in[1];
    const size_t grid_bytes = (size_t)G3 * 12 * 2;   // 98,304,000
    const bool fast = (ws_size >= grid_bytes);

    if (fast) {
        u16* wsgrid = (u16*)d_ws;
        transpose_k0<u16, 0><<<dim3(G*G), dim3(64), 0, stream>>>(
            (const u16*)d_in[3], wsgrid, rdraw);
        transpose_k0<float, 1><<<dim3(G*G), dim3(64), 0, stream>>>(
            (const float*)d_in[3], wsgrid, rdraw);

        dvgo_fused<u16, u16, 0, 1><<<dim3(NRAYS), dim3(256), 0, stream>>>(
            (const u16*)d_in[0], (const u16*)d_in[1], (const u16*)d_in[2],
            (const u16*)d_in[3], (const u16*)d_in[4], (const u16*)d_in[5],
            (const u16*)d_in[6], (const u16*)d_in[7], (const u16*)d_in[8],
            (const u16*)d_in[9], (u16*)d_out, rdraw, wsgrid);
        dvgo_fused<float, float, 1, 1><<<dim3(NRAYS), dim3(256), 0, stream>>>(
            (const float*)d_in[0], (const float*)d_in[1], (const float*)d_in[2],
            (const float*)d_in[3], (const float*)d_in[4], (const float*)d_in[5],
            (const float*)d_in[6], (const float*)d_in[7], (const float*)d_in[8],
            (const float*)d_in[9], (float*)d_out, rdraw, wsgrid);
    } else {
        dvgo_fused<u16, u16, 0, 0><<<dim3(NRAYS), dim3(256), 0, stream>>>(
            (const u16*)d_in[0], (const u16*)d_in[1], (const u16*)d_in[2],
            (const u16*)d_in[3], (const u16*)d_in[4], (const u16*)d_in[5],
            (const u16*)d_in[6], (const u16*)d_in[7], (const u16*)d_in[8],
            (const u16*)d_in[9], (u16*)d_out, rdraw, nullptr);
        dvgo_fused<float, float, 1, 0><<<dim3(NRAYS), dim3(256), 0, stream>>>(
            (const float*)d_in[0], (const float*)d_in[1], (const float*)d_in[2],
            (const float*)d_in[3], (const float*)d_in[4], (const float*)d_in[5],
            (const float*)d_in[6], (const float*)d_in[7], (const float*)d_in[8],
            (const float*)d_in[9], (float*)d_out, rdraw, nullptr);
    }
}